// Round 1
// baseline (2880.648 us; speedup 1.0000x reference)
//
#include <hip/hip_runtime.h>
#include <hip/hip_bf16.h>

#define B_ 16384
#define T_ 128
#define E_ 32
#define H_ 128
#define G3_ 384
#define V_ 30001
#define D_ 128
#define C_ 3

__device__ __forceinline__ float frcp_(float x) { return __builtin_amdgcn_rcpf(x); }
__device__ __forceinline__ float fsigm_(float x) {
    x = fmaxf(-40.f, fminf(40.f, x));
    return frcp_(1.f + __expf(-x));
}
__device__ __forceinline__ float ftanh_(float x) {
    x = fmaxf(-20.f, fminf(20.f, x));
    float e = __expf(2.f * x);
    return (e - 1.f) * frcp_(e + 1.f);
}

// ---------------- Kernel 1: embW[v][g] = emb[v][:] @ W[:][g] + b_in[g] ----------------
#define K1_ROWS 8
__global__ __launch_bounds__(384) void embw_kernel(
    const float* __restrict__ emb,   // [V][32]
    const float* __restrict__ W,     // [32][384]
    const float* __restrict__ b_in,  // [384] (= b row 0)
    float* __restrict__ embW)        // [V][384]
{
    __shared__ float sW[E_][G3_];        // 48 KB
    __shared__ float sE[K1_ROWS][E_];
    const int g = threadIdx.x;           // 0..383
    #pragma unroll
    for (int e = 0; e < E_; ++e) sW[e][g] = W[e * G3_ + g];
    const int v0 = blockIdx.x * K1_ROWS;
    for (int idx = g; idx < K1_ROWS * E_; idx += 384) {
        int rr = idx >> 5, ee = idx & 31;
        int v = v0 + rr;
        sE[rr][ee] = (v < V_) ? emb[v * E_ + ee] : 0.f;
    }
    __syncthreads();
    const float bg = b_in[g];
    #pragma unroll
    for (int rr = 0; rr < K1_ROWS; ++rr) {
        int v = v0 + rr;
        if (v >= V_) break;
        float acc = bg;
        #pragma unroll
        for (int e = 0; e < E_; ++e) acc = fmaf(sE[rr][e], sW[e][g], acc);
        embW[(size_t)v * G3_ + g] = acc;
    }
}

// ---------------- Kernel 2: GRU over T=128 + dense head + softmax ----------------
// 256 blocks x 256 threads; each block owns 64 batch rows.
// Thread (rg = tid>>5 in [0,8), cg = tid&31 in [0,32)) owns rows r=rg*8+i (i<8),
// cols c=cg*4+l (l<4). h kept in LDS (for the GEMM) AND in this thread's regs
// (for the gate update -> no LDS read-back, no bank conflicts).
__global__ __launch_bounds__(256, 1) void gru_head_kernel(
    const int*   __restrict__ tokens,  // [B][T]
    const float* __restrict__ embW,    // [V][384]  (includes input bias)
    const float* __restrict__ U,       // [128][384]
    const float* __restrict__ brec,    // [384] (= b row 1)
    const float* __restrict__ W1,      // [128][128]
    const float* __restrict__ b1,      // [128]
    const float* __restrict__ Wout,    // [128][3]
    const float* __restrict__ bout,    // [3]
    float* __restrict__ out)           // [B][3]
{
    __shared__ float sh[64][H_ + 4];   // padded: gate-phase float4 writes 4-way max
    __shared__ int   stok[64][T_];     // 32 KB
    __shared__ float sd[64][D_ + 4];

    const int tid = threadIdx.x;
    const int rg  = tid >> 5;
    const int cg  = tid & 31;
    const int c0  = cg * 4;
    const int b0r = blockIdx.x * 64;

    // stage this tile's tokens (coalesced int4)
    {
        const int4* tp = (const int4*)(tokens + (size_t)b0r * T_);
        int4* sp = (int4*)(&stok[0][0]);
        #pragma unroll
        for (int it = 0; it < 8; ++it) sp[tid + 256 * it] = tp[tid + 256 * it];
    }

    // recurrent biases for this thread's 4 columns
    const float4 bzv = *(const float4*)(brec + c0);
    const float4 brv = *(const float4*)(brec + 128 + c0);
    const float4 bhv = *(const float4*)(brec + 256 + c0);
    const float bz[4] = {bzv.x, bzv.y, bzv.z, bzv.w};
    const float br[4] = {brv.x, brv.y, brv.z, brv.w};
    const float bh[4] = {bhv.x, bhv.y, bhv.z, bhv.w};

    float hreg[8][4];
    #pragma unroll
    for (int i = 0; i < 8; ++i) {
        #pragma unroll
        for (int l = 0; l < 4; ++l) hreg[i][l] = 0.f;
        *(float4*)(&sh[rg * 8 + i][c0]) = make_float4(0.f, 0.f, 0.f, 0.f);
    }
    __syncthreads();

    for (int t = 0; t < T_; ++t) {
        // ---- rec = h @ U + brec ----
        float az[8][4], ar[8][4], ah[8][4];
        #pragma unroll
        for (int i = 0; i < 8; ++i)
            #pragma unroll
            for (int l = 0; l < 4; ++l) { az[i][l] = bz[l]; ar[i][l] = br[l]; ah[i][l] = bh[l]; }

        #pragma unroll 4
        for (int k = 0; k < H_; ++k) {
            const float* uk = U + (size_t)k * G3_ + c0;
            const float4 uzv = *(const float4*)(uk);
            const float4 urv = *(const float4*)(uk + 128);
            const float4 uhv = *(const float4*)(uk + 256);
            const float uz[4] = {uzv.x, uzv.y, uzv.z, uzv.w};
            const float ur[4] = {urv.x, urv.y, urv.z, urv.w};
            const float uh[4] = {uhv.x, uhv.y, uhv.z, uhv.w};
            #pragma unroll
            for (int i = 0; i < 8; ++i) {
                const float hv = sh[rg * 8 + i][k];   // broadcast read
                #pragma unroll
                for (int l = 0; l < 4; ++l) {
                    az[i][l] = fmaf(hv, uz[l], az[i][l]);
                    ar[i][l] = fmaf(hv, ur[l], ar[i][l]);
                    ah[i][l] = fmaf(hv, uh[l], ah[i][l]);
                }
            }
        }
        __syncthreads();   // all reads of sh done before anyone rewrites it

        // ---- gates + state update ----
        #pragma unroll
        for (int i = 0; i < 8; ++i) {
            const int r = rg * 8 + i;
            const int tok = stok[r][t];
            const float* xp = embW + (size_t)tok * G3_ + c0;
            const float4 xzv = *(const float4*)(xp);
            const float4 xrv = *(const float4*)(xp + 128);
            const float4 xhv = *(const float4*)(xp + 256);
            const float xz[4] = {xzv.x, xzv.y, xzv.z, xzv.w};
            const float xr[4] = {xrv.x, xrv.y, xrv.z, xrv.w};
            const float xh[4] = {xhv.x, xhv.y, xhv.z, xhv.w};
            float hn[4];
            #pragma unroll
            for (int l = 0; l < 4; ++l) {
                const float z  = fsigm_(xz[l] + az[i][l]);
                const float rr = fsigm_(xr[l] + ar[i][l]);
                const float hh = ftanh_(xh[l] + rr * ah[i][l]);
                float v = z * hreg[i][l] + (1.f - z) * hh;
                v = (tok != 0) ? v : hreg[i][l];
                hn[l] = v;
                hreg[i][l] = v;
            }
            *(float4*)(&sh[r][c0]) = make_float4(hn[0], hn[1], hn[2], hn[3]);
        }
        __syncthreads();
    }

    // ---- head: d = swish(h @ W1 + b1) ----
    const float4 bdv = *(const float4*)(b1 + c0);
    const float bd[4] = {bdv.x, bdv.y, bdv.z, bdv.w};
    float ad[8][4];
    #pragma unroll
    for (int i = 0; i < 8; ++i)
        #pragma unroll
        for (int l = 0; l < 4; ++l) ad[i][l] = bd[l];

    #pragma unroll 4
    for (int k = 0; k < H_; ++k) {
        const float4 wv = *(const float4*)(W1 + (size_t)k * D_ + c0);
        const float w4[4] = {wv.x, wv.y, wv.z, wv.w};
        #pragma unroll
        for (int i = 0; i < 8; ++i) {
            const float hv = sh[rg * 8 + i][k];
            #pragma unroll
            for (int l = 0; l < 4; ++l) ad[i][l] = fmaf(hv, w4[l], ad[i][l]);
        }
    }
    #pragma unroll
    for (int i = 0; i < 8; ++i) {
        float dv[4];
        #pragma unroll
        for (int l = 0; l < 4; ++l) { const float v = ad[i][l]; dv[l] = v * fsigm_(v); }
        *(float4*)(&sd[rg * 8 + i][c0]) = make_float4(dv[0], dv[1], dv[2], dv[3]);
    }
    __syncthreads();

    // ---- logits + softmax (one thread per row) ----
    if (tid < 64) {
        const int r = tid;
        float l0 = bout[0], l1 = bout[1], l2 = bout[2];
        #pragma unroll 4
        for (int k = 0; k < D_; ++k) {
            const float dv = sd[r][k];
            l0 = fmaf(dv, Wout[k * 3 + 0], l0);
            l1 = fmaf(dv, Wout[k * 3 + 1], l1);
            l2 = fmaf(dv, Wout[k * 3 + 2], l2);
        }
        const float mx = fmaxf(l0, fmaxf(l1, l2));
        const float e0 = __expf(l0 - mx), e1 = __expf(l1 - mx), e2 = __expf(l2 - mx);
        const float inv = frcp_(e0 + e1 + e2);
        float* op = out + (size_t)(b0r + r) * 3;
        op[0] = e0 * inv;
        op[1] = e1 * inv;
        op[2] = e2 * inv;
    }
}

extern "C" void kernel_launch(void* const* d_in, const int* in_sizes, int n_in,
                              void* d_out, int out_size, void* d_ws, size_t ws_size,
                              hipStream_t stream) {
    (void)in_sizes; (void)n_in; (void)out_size; (void)ws_size;
    const int*   tokens = (const int*)d_in[0];
    const float* emb    = (const float*)d_in[1];
    const float* W      = (const float*)d_in[2];
    const float* U      = (const float*)d_in[3];
    const float* b      = (const float*)d_in[4];
    const float* W1     = (const float*)d_in[5];
    const float* b1     = (const float*)d_in[6];
    const float* Wout   = (const float*)d_in[7];
    const float* bout   = (const float*)d_in[8];
    float* out  = (float*)d_out;
    float* embW = (float*)d_ws;   // [V][384] f32 = 46,081,536 bytes of scratch

    hipLaunchKernelGGL(embw_kernel, dim3((V_ + K1_ROWS - 1) / K1_ROWS), dim3(384), 0, stream,
                       emb, W, b, embW);
    hipLaunchKernelGGL(gru_head_kernel, dim3(B_ / 64), dim3(256), 0, stream,
                       tokens, embW, U, b + G3_, W1, b1, Wout, bout, out);
}

// Round 2
// 631.548 us; speedup vs baseline: 4.5612x; 4.5612x over previous
//
#include <hip/hip_runtime.h>
#include <hip/hip_fp16.h>

#define B_ 16384
#define T_ 128
#define E_ 32
#define H_ 128
#define G3_ 384
#define V_ 30001
#define D_ 128
#define C_ 3

typedef _Float16 f16;
typedef f16 f16x8 __attribute__((ext_vector_type(8)));
typedef float f32x4 __attribute__((ext_vector_type(4)));

// ---- LDS geometry (bytes) ----
#define UT_PITCH   272                        // 136 f16/row (128 used), 16B aligned
#define UT_BYTES   (G3_ * UT_PITCH)           // 104448
#define ASCR_PITCH 272                        // per-wave h scratch row pitch
#define ASCR_BYTES (16 * ASCR_PITCH)          // 4352 per wave
#define BIAS_OFF   (UT_BYTES + 4 * ASCR_BYTES)    // 121856
#define DBUF_OFF   (BIAS_OFF + G3_ * 4)           // 123392
#define DBUF_PITCH 528                        // 132 f32
#define LDS_TOTAL  (DBUF_OFF + 4 * 16 * DBUF_PITCH)  // 157184 < 160K

__device__ __forceinline__ float frcp_(float x) { return __builtin_amdgcn_rcpf(x); }
__device__ __forceinline__ float fsigm_(float x) {
    x = fmaxf(-40.f, fminf(40.f, x));
    return frcp_(1.f + __expf(-x));
}
__device__ __forceinline__ float ftanh_(float x) {
    x = fmaxf(-20.f, fminf(20.f, x));
    float e = __expf(2.f * x);
    return (e - 1.f) * frcp_(e + 1.f);
}

// ---------------- Kernel 1: embW[v][g] = emb[v][:] @ W[:][g] + b0[g] ----------------
#define K1_ROWS 8
__global__ __launch_bounds__(384) void embw_kernel(
    const float* __restrict__ emb,   // [V][32]
    const float* __restrict__ W,     // [32][384]
    const float* __restrict__ b_in,  // [384] (= b row 0)
    float* __restrict__ embW)        // [V][384]
{
    __shared__ float sW[E_][G3_];
    __shared__ float sE[K1_ROWS][E_];
    const int g = threadIdx.x;
    #pragma unroll
    for (int e = 0; e < E_; ++e) sW[e][g] = W[e * G3_ + g];
    const int v0 = blockIdx.x * K1_ROWS;
    for (int idx = g; idx < K1_ROWS * E_; idx += 384) {
        int rr = idx >> 5, ee = idx & 31;
        int v = v0 + rr;
        sE[rr][ee] = (v < V_) ? emb[v * E_ + ee] : 0.f;
    }
    __syncthreads();
    const float bg = b_in[g];
    #pragma unroll
    for (int rr = 0; rr < K1_ROWS; ++rr) {
        int v = v0 + rr;
        if (v >= V_) break;
        float acc = bg;
        #pragma unroll
        for (int e = 0; e < E_; ++e) acc = fmaf(sE[rr][e], sW[e][g], acc);
        embW[(size_t)v * G3_ + g] = acc;
    }
}

// ---------------- Kernel 2: MFMA GRU + head ----------------
// 256 blocks x 256 threads (4 waves). Wave w owns 16 batch rows exclusively:
// no __syncthreads in the T-loop; h recirculates through a per-wave LDS
// scratch (wave-synchronous lgkmcnt ordering only).
// MFMA 16x16x32 f16 layouts (guide-verified):
//   A: lane l holds A[l&15][(l>>4)*8 + j]      (8 f16 = 1 b128 read)
//   B: lane l holds B[(l>>4)*8 + j][l&15]      (U^T rows make this contiguous)
//   C/D: lane l, reg i -> row=(l>>4)*4+i, col=l&15
__global__ __launch_bounds__(256, 1) void gru_mfma_kernel(
    const int*   __restrict__ tokens,  // [B][T]
    const float* __restrict__ embW,    // [V][384] (includes input bias b0)
    const float* __restrict__ U,       // [128][384]
    const float* __restrict__ b,       // [2][384]
    const float* __restrict__ W1,      // [128][128]
    const float* __restrict__ b1,      // [128]
    const float* __restrict__ Wout,    // [128][3]
    const float* __restrict__ bout,    // [3]
    float* __restrict__ out)           // [B][3]
{
    __shared__ char lds[LDS_TOTAL];
    const int tid = threadIdx.x;

    // ---- stage U^T as f16: UT[c][k] = U[k][c]; U flat idx = k*384+c (coalesced) ----
    for (int idx = tid; idx < G3_ * H_; idx += 256) {
        int c = idx % G3_, k = idx / G3_;
        *(f16*)(&lds[c * UT_PITCH + k * 2]) = (f16)U[idx];
    }
    // ---- recurrent bias b1 (f32) ----
    for (int idx = tid; idx < G3_; idx += 256)
        *(float*)(&lds[BIAS_OFF + idx * 4]) = b[G3_ + idx];
    __syncthreads();

    const int w  = tid >> 6;
    const int l  = tid & 63;
    const int cl = l & 15;    // col-in-tile / A-frag row
    const int q  = l >> 4;    // 0..3
    const int R0 = blockIdx.x * 64 + w * 16;
    char* Ascr = &lds[UT_BYTES + w * ASCR_BYTES];

    // zero h scratch (own wave only)
    {
        const f16x8 z8 = {0, 0, 0, 0, 0, 0, 0, 0};
        for (int idx = l; idx < ASCR_BYTES / 16; idx += 64)
            *(f16x8*)(Ascr + idx * 16) = z8;
    }

    float hreg[8][4];
    #pragma unroll
    for (int g = 0; g < 8; ++g)
        #pragma unroll
        for (int i = 0; i < 4; ++i) hreg[g][i] = 0.f;

    // recurrent biases for this lane's columns (b is zeros in this problem,
    // but honored for correctness): z col = 16g+cl, r col = 128+16g+cl,
    // h col = 256+16g+cl (b1 part only; b0 already folded into embW).
    float bz[8], br[8], bh[8];
    #pragma unroll
    for (int g = 0; g < 8; ++g) {
        bz[g] = *(const float*)(&lds[BIAS_OFF + (g * 16 + cl) * 4]);
        br[g] = *(const float*)(&lds[BIAS_OFF + (128 + g * 16 + cl) * 4]);
        bh[g] = *(const float*)(&lds[BIAS_OFF + (256 + g * 16 + cl) * 4]);
    }

    const int kA = q * 8;  // A/B-frag k base within a k-tile

    for (int t = 0; t < T_; ++t) {
        // tokens for this lane's 4 gate rows (rows 4q..4q+3)
        int tk[4];
        const float* xb[4];
        #pragma unroll
        for (int i = 0; i < 4; ++i) {
            tk[i] = tokens[(R0 + 4 * q + i) * T_ + t];
            xb[i] = embW + (size_t)tk[i] * G3_ + cl;
        }

        // A-fragments: h at step t (written by this wave at step t-1)
        f16x8 af[4];
        #pragma unroll
        for (int kt = 0; kt < 4; ++kt)
            af[kt] = *(const f16x8*)(Ascr + cl * ASCR_PITCH + (kt * 32 + kA) * 2);

        float xz[8][4], xr[8][4], xh[8][4];
        auto loadxg = [&](int g) {
            #pragma unroll
            for (int i = 0; i < 4; ++i) {
                const float* p = xb[i] + g * 16;
                xz[g][i] = p[0];
                xr[g][i] = p[128];
                xh[g][i] = p[256];
            }
        };
        // prefetch depth 3 (hidden under MFMAs)
        loadxg(0); loadxg(1); loadxg(2);

        #pragma unroll
        for (int g = 0; g < 8; ++g) {
            f32x4 accz = {bz[g], bz[g], bz[g], bz[g]};
            f32x4 accr = {br[g], br[g], br[g], br[g]};
            f32x4 acch = {bh[g], bh[g], bh[g], bh[g]};
            #pragma unroll
            for (int kt = 0; kt < 4; ++kt) {
                const int kb = (kt * 32 + kA) * 2;
                f16x8 bfz = *(const f16x8*)(&lds[(g * 16 + cl) * UT_PITCH + kb]);
                f16x8 bfr = *(const f16x8*)(&lds[(128 + g * 16 + cl) * UT_PITCH + kb]);
                f16x8 bfh = *(const f16x8*)(&lds[(256 + g * 16 + cl) * UT_PITCH + kb]);
                accz = __builtin_amdgcn_mfma_f32_16x16x32_f16(af[kt], bfz, accz, 0, 0, 0);
                accr = __builtin_amdgcn_mfma_f32_16x16x32_f16(af[kt], bfr, accr, 0, 0, 0);
                acch = __builtin_amdgcn_mfma_f32_16x16x32_f16(af[kt], bfh, acch, 0, 0, 0);
            }
            if (g < 5) loadxg(g + 3);

            // gates for 4 elements: (row = 4q+i, col = 16g+cl)
            #pragma unroll
            for (int i = 0; i < 4; ++i) {
                const float z  = fsigm_(xz[g][i] + accz[i]);
                const float r  = fsigm_(xr[g][i] + accr[i]);
                const float hh = ftanh_(xh[g][i] + r * acch[i]);
                float hn = z * hreg[g][i] + (1.f - z) * hh;
                hn = (tk[i] != 0) ? hn : hreg[g][i];
                hreg[g][i] = hn;
                *(f16*)(Ascr + (4 * q + i) * ASCR_PITCH + (g * 16 + cl) * 2) = (f16)hn;
            }
        }
    }

    // ---- head ----
    __syncthreads();   // all waves done with UT; reuse it for W1^T
    for (int idx = tid; idx < H_ * D_; idx += 256) {
        int c = idx & 127, k = idx >> 7;   // W1 flat idx = k*128+c (coalesced)
        *(f16*)(&lds[c * UT_PITCH + k * 2]) = (f16)W1[idx];
    }
    __syncthreads();

    char* dbuf = &lds[DBUF_OFF + w * 16 * DBUF_PITCH];
    {
        f16x8 af[4];
        #pragma unroll
        for (int kt = 0; kt < 4; ++kt)
            af[kt] = *(const f16x8*)(Ascr + cl * ASCR_PITCH + (kt * 32 + kA) * 2);
        #pragma unroll
        for (int g = 0; g < 8; ++g) {
            const float bd = b1[g * 16 + cl];
            f32x4 acc = {bd, bd, bd, bd};
            #pragma unroll
            for (int kt = 0; kt < 4; ++kt) {
                f16x8 bw = *(const f16x8*)(&lds[(g * 16 + cl) * UT_PITCH + (kt * 32 + kA) * 2]);
                acc = __builtin_amdgcn_mfma_f32_16x16x32_f16(af[kt], bw, acc, 0, 0, 0);
            }
            #pragma unroll
            for (int i = 0; i < 4; ++i) {
                const float v = acc[i];
                *(float*)(dbuf + (4 * q + i) * DBUF_PITCH + (g * 16 + cl) * 4) = v * fsigm_(v);
            }
        }
    }

    // logits + softmax: 48 lanes = 16 rows x 3 classes
    if (l < 48) {
        const int row = l & 15, ci = l >> 4;
        float acc = bout[ci];
        #pragma unroll 4
        for (int k = 0; k < D_; ++k)
            acc = fmaf(*(const float*)(dbuf + row * DBUF_PITCH + k * 4), Wout[k * 3 + ci], acc);
        const float v0 = __shfl(acc, row);
        const float v1 = __shfl(acc, row + 16);
        const float v2 = __shfl(acc, row + 32);
        const float mx = fmaxf(v0, fmaxf(v1, v2));
        const float e0 = __expf(v0 - mx), e1 = __expf(v1 - mx), e2 = __expf(v2 - mx);
        const float inv = frcp_(e0 + e1 + e2);
        const float mine = (ci == 0) ? e0 : (ci == 1) ? e1 : e2;
        out[(size_t)(R0 + row) * 3 + ci] = mine * inv;
    }
}

extern "C" void kernel_launch(void* const* d_in, const int* in_sizes, int n_in,
                              void* d_out, int out_size, void* d_ws, size_t ws_size,
                              hipStream_t stream) {
    (void)in_sizes; (void)n_in; (void)out_size; (void)ws_size;
    const int*   tokens = (const int*)d_in[0];
    const float* emb    = (const float*)d_in[1];
    const float* W      = (const float*)d_in[2];
    const float* U      = (const float*)d_in[3];
    const float* b      = (const float*)d_in[4];
    const float* W1     = (const float*)d_in[5];
    const float* b1     = (const float*)d_in[6];
    const float* Wout   = (const float*)d_in[7];
    const float* bout   = (const float*)d_in[8];
    float* out  = (float*)d_out;
    float* embW = (float*)d_ws;   // [V][384] f32 (same 46 MB footprint as round 1)

    hipLaunchKernelGGL(embw_kernel, dim3((V_ + K1_ROWS - 1) / K1_ROWS), dim3(384), 0, stream,
                       emb, W, b, embW);
    hipLaunchKernelGGL(gru_mfma_kernel, dim3(B_ / 64), dim3(256), 0, stream,
                       tokens, embW, U, b, W1, b1, Wout, bout, out);
}

// Round 3
// 439.458 us; speedup vs baseline: 6.5550x; 1.4371x over previous
//
#include <hip/hip_runtime.h>
#include <hip/hip_fp16.h>

#define B_ 16384
#define T_ 128
#define E_ 32
#define H_ 128
#define G3_ 384
#define V_ 30001
#define D_ 128
#define C_ 3

typedef _Float16 f16;
typedef f16 f16x8 __attribute__((ext_vector_type(8)));
typedef float f32x4 __attribute__((ext_vector_type(4)));

// ---- LDS layout (bytes), 256-thread block, 32 batch rows ----
#define HPITCH   272                 // h row pitch: 128 f16 used, pad to 17*16B
#define H0_OFF   0                   // h buffer 0: 32*272 = 8704
#define H1_OFF   8704                // h buffer 1
#define TOK_OFF  17408               // stok u16 [32][136] = 8704 B
#define DBUF_OFF 26112               // head dbuf f32 [32][132] = 16896 B
#define LDS_TOTAL 43008

__device__ __forceinline__ float frcp_(float x) { return __builtin_amdgcn_rcpf(x); }
// inf-safe, clamp-free: sigmoid(+-inf)=1/0, tanh(+-inf)=+-1
__device__ __forceinline__ float fsigm_(float x) {
    return frcp_(1.f + __expf(-x));
}
__device__ __forceinline__ float ftanh_(float x) {
    return fmaf(-2.f, frcp_(1.f + __expf(2.f * x)), 1.f);
}

// ---------------- Kernel 1: embW16[v][g] = f16(emb[v][:] @ W[:][g] + b0[g]) ----------------
#define K1_ROWS 8
__global__ __launch_bounds__(384) void embw_kernel(
    const float* __restrict__ emb,   // [V][32]
    const float* __restrict__ W,     // [32][384]
    const float* __restrict__ b_in,  // [384] (= b row 0)
    f16* __restrict__ embW)          // [V][384] f16
{
    __shared__ float sW[E_][G3_];
    __shared__ float sE[K1_ROWS][E_];
    const int g = threadIdx.x;
    #pragma unroll
    for (int e = 0; e < E_; ++e) sW[e][g] = W[e * G3_ + g];
    const int v0 = blockIdx.x * K1_ROWS;
    for (int idx = g; idx < K1_ROWS * E_; idx += 384) {
        int rr = idx >> 5, ee = idx & 31;
        int v = v0 + rr;
        sE[rr][ee] = (v < V_) ? emb[v * E_ + ee] : 0.f;
    }
    __syncthreads();
    const float bg = b_in[g];
    #pragma unroll
    for (int rr = 0; rr < K1_ROWS; ++rr) {
        int v = v0 + rr;
        if (v >= V_) break;
        float acc = bg;
        #pragma unroll
        for (int e = 0; e < E_; ++e) acc = fmaf(sE[rr][e], sW[e][g], acc);
        embW[(size_t)v * G3_ + g] = (f16)acc;
    }
}

// ---------------- Kernel 2: GRU with U persistent in VGPRs ----------------
// 512 blocks x 256 threads (4 waves). Block owns 32 batch rows; wave w owns
// h-cols [32w, 32w+32). Each wave keeps its U slice (24 f16x8 frags = 96 VGPR)
// in registers for the whole kernel -> zero LDS B-traffic. h is double-buffered
// in LDS (f16, the MFMA A operand path); one __syncthreads per step.
// MFMA 16x16x32 f16 layouts (verified in round 2):
//   A: lane l holds A[l&15][(l>>4)*8 + j]
//   B: lane l holds B[(l>>4)*8 + j][l&15]
//   C/D: lane l, reg i -> row=(l>>4)*4+i, col=l&15
__global__ __launch_bounds__(256, 2) void gru_mfma_kernel(
    const int*   __restrict__ tokens,  // [B][T]
    const f16*   __restrict__ embW,    // [V][384] f16 (includes input bias b0)
    const float* __restrict__ U,       // [128][384]
    const float* __restrict__ b,       // [2][384]
    const float* __restrict__ W1,      // [128][128]
    const float* __restrict__ b1,      // [128]
    const float* __restrict__ Wout,    // [128][3]
    const float* __restrict__ bout,    // [3]
    float* __restrict__ out)           // [B][3]
{
    __shared__ char lds[LDS_TOTAL];
    const int tid = threadIdx.x;
    const int w   = tid >> 6;       // wave = h-col group, 0..3
    const int l   = tid & 63;
    const int cl  = l & 15;
    const int q   = l >> 4;         // 0..3
    const int R0  = blockIdx.x * 32;

    // ---- stage tokens as u16 (max token 30000 < 65536) ----
    for (int idx = tid; idx < 32 * T_; idx += 256) {
        int r = idx >> 7, t = idx & 127;
        *(unsigned short*)(&lds[TOK_OFF + r * HPITCH + t * 2]) =
            (unsigned short)tokens[(size_t)(R0 + r) * T_ + t];
    }
    // ---- zero h buffer 0 ----
    for (int idx = tid; idx < H1_OFF / 4; idx += 256)
        ((float*)lds)[idx] = 0.f;

    // ---- persistent U fragments (one-time strided global read, L2-hot) ----
    // Bf[g][gate][kt]: lane holds U[kt*32+q*8+j][gate*128 + w*32 + g*16 + cl]
    f16x8 Bf[2][3][4];
    #pragma unroll
    for (int g = 0; g < 2; ++g)
        #pragma unroll
        for (int gt = 0; gt < 3; ++gt) {
            const int n = gt * 128 + w * 32 + g * 16 + cl;
            #pragma unroll
            for (int kt = 0; kt < 4; ++kt) {
                const int k0 = kt * 32 + q * 8;
                f16x8 fr;
                #pragma unroll
                for (int j = 0; j < 8; ++j)
                    fr[j] = (f16)U[(size_t)(k0 + j) * G3_ + n];
                Bf[g][gt][kt] = fr;
            }
        }

    // recurrent biases for this lane's 2 col-tiles
    float bz[2], br[2], bh[2];
    #pragma unroll
    for (int g = 0; g < 2; ++g) {
        const int col = w * 32 + g * 16 + cl;
        bz[g] = b[G3_ + col];
        br[g] = b[G3_ + 128 + col];
        bh[g] = b[G3_ + 256 + col];
    }

    float hreg[2][2][4];   // [rt][g][i]
    #pragma unroll
    for (int rt = 0; rt < 2; ++rt)
        #pragma unroll
        for (int g = 0; g < 2; ++g)
            #pragma unroll
            for (int i = 0; i < 4; ++i) hreg[rt][g][i] = 0.f;

    __syncthreads();

    int cur = 0;
    for (int t = 0; t < T_; ++t) {
        const char* hb = &lds[cur ? H1_OFF : H0_OFF];
        char*       hn = &lds[cur ? H0_OFF : H1_OFF];

        // tokens for this lane's 8 rows (rows rt*16 + 4q + i)
        int tk[2][4];
        #pragma unroll
        for (int rt = 0; rt < 2; ++rt)
            #pragma unroll
            for (int i = 0; i < 4; ++i)
                tk[rt][i] = *(const unsigned short*)
                    (&lds[TOK_OFF + (rt * 16 + 4 * q + i) * HPITCH + t * 2]);

        // gather xg (f16 table, 48 scalar loads; hidden under MFMAs by scheduler)
        float xz[2][2][4], xr[2][2][4], xh[2][2][4];
        #pragma unroll
        for (int rt = 0; rt < 2; ++rt)
            #pragma unroll
            for (int i = 0; i < 4; ++i) {
                const f16* xp = embW + (size_t)tk[rt][i] * G3_ + w * 32 + cl;
                #pragma unroll
                for (int g = 0; g < 2; ++g) {
                    xz[rt][g][i] = (float)xp[g * 16];
                    xr[rt][g][i] = (float)xp[128 + g * 16];
                    xh[rt][g][i] = (float)xp[256 + g * 16];
                }
            }

        #pragma unroll
        for (int g = 0; g < 2; ++g) {
            f32x4 acc[2][3];
            #pragma unroll
            for (int rt = 0; rt < 2; ++rt) {
                acc[rt][0] = (f32x4){bz[g], bz[g], bz[g], bz[g]};
                acc[rt][1] = (f32x4){br[g], br[g], br[g], br[g]};
                acc[rt][2] = (f32x4){bh[g], bh[g], bh[g], bh[g]};
            }
            #pragma unroll
            for (int kt = 0; kt < 4; ++kt) {
                const f16x8 a0 = *(const f16x8*)(hb + (cl)      * HPITCH + kt * 64 + q * 16);
                const f16x8 a1 = *(const f16x8*)(hb + (16 + cl) * HPITCH + kt * 64 + q * 16);
                #pragma unroll
                for (int gt = 0; gt < 3; ++gt) {
                    acc[0][gt] = __builtin_amdgcn_mfma_f32_16x16x32_f16(a0, Bf[g][gt][kt], acc[0][gt], 0, 0, 0);
                    acc[1][gt] = __builtin_amdgcn_mfma_f32_16x16x32_f16(a1, Bf[g][gt][kt], acc[1][gt], 0, 0, 0);
                }
            }
            // gates + state update for this col-tile
            #pragma unroll
            for (int rt = 0; rt < 2; ++rt)
                #pragma unroll
                for (int i = 0; i < 4; ++i) {
                    const float z  = fsigm_(xz[rt][g][i] + acc[rt][0][i]);
                    const float r  = fsigm_(xr[rt][g][i] + acc[rt][1][i]);
                    const float hh = ftanh_(fmaf(r, acc[rt][2][i], xh[rt][g][i]));
                    const float hv = hreg[rt][g][i];
                    float nv = hh + z * (hv - hh);
                    nv = (tk[rt][i] != 0) ? nv : hv;
                    hreg[rt][g][i] = nv;
                    *(f16*)(hn + (rt * 16 + 4 * q + i) * HPITCH
                               + (w * 32 + g * 16 + cl) * 2) = (f16)nv;
                }
        }
        __syncthreads();
        cur ^= 1;
    }
    // T_=128 even -> final h is in buffer 0

    // ---- head: d = swish(h @ W1 + b1) ----
    f16x8 Wf[2][4];
    #pragma unroll
    for (int ct = 0; ct < 2; ++ct) {
        const int n = w * 32 + ct * 16 + cl;
        #pragma unroll
        for (int kt = 0; kt < 4; ++kt) {
            const int k0 = kt * 32 + q * 8;
            f16x8 fr;
            #pragma unroll
            for (int j = 0; j < 8; ++j)
                fr[j] = (f16)W1[(size_t)(k0 + j) * D_ + n];
            Wf[ct][kt] = fr;
        }
    }
    {
        const char* hb = &lds[H0_OFF];
        f32x4 dacc[2][2];
        #pragma unroll
        for (int rt = 0; rt < 2; ++rt)
            #pragma unroll
            for (int ct = 0; ct < 2; ++ct) {
                const float bd = b1[w * 32 + ct * 16 + cl];
                dacc[rt][ct] = (f32x4){bd, bd, bd, bd};
            }
        #pragma unroll
        for (int kt = 0; kt < 4; ++kt) {
            const f16x8 a0 = *(const f16x8*)(hb + (cl)      * HPITCH + kt * 64 + q * 16);
            const f16x8 a1 = *(const f16x8*)(hb + (16 + cl) * HPITCH + kt * 64 + q * 16);
            #pragma unroll
            for (int ct = 0; ct < 2; ++ct) {
                dacc[0][ct] = __builtin_amdgcn_mfma_f32_16x16x32_f16(a0, Wf[ct][kt], dacc[0][ct], 0, 0, 0);
                dacc[1][ct] = __builtin_amdgcn_mfma_f32_16x16x32_f16(a1, Wf[ct][kt], dacc[1][ct], 0, 0, 0);
            }
        }
        #pragma unroll
        for (int rt = 0; rt < 2; ++rt)
            #pragma unroll
            for (int ct = 0; ct < 2; ++ct)
                #pragma unroll
                for (int i = 0; i < 4; ++i) {
                    const float v = dacc[rt][ct][i];
                    *(float*)(&lds[DBUF_OFF + (rt * 16 + 4 * q + i) * 528
                                   + (w * 32 + ct * 16 + cl) * 4]) = v * fsigm_(v);
                }
    }
    __syncthreads();

    // ---- logits + softmax: waves 0,1 cover rows 0..31 (48 lanes each) ----
    if (w < 2 && l < 48) {
        const int row = l & 15, ci = l >> 4;
        const int r = 16 * w + row;
        float acc = bout[ci];
        #pragma unroll 4
        for (int k = 0; k < D_; ++k)
            acc = fmaf(*(const float*)(&lds[DBUF_OFF + r * 528 + k * 4]),
                       Wout[k * 3 + ci], acc);
        const float v0 = __shfl(acc, row);
        const float v1 = __shfl(acc, row + 16);
        const float v2 = __shfl(acc, row + 32);
        const float mx = fmaxf(v0, fmaxf(v1, v2));
        const float e0 = __expf(v0 - mx), e1 = __expf(v1 - mx), e2 = __expf(v2 - mx);
        const float inv = frcp_(e0 + e1 + e2);
        const float mine = (ci == 0) ? e0 : (ci == 1) ? e1 : e2;
        out[(size_t)(R0 + r) * 3 + ci] = mine * inv;
    }
}

extern "C" void kernel_launch(void* const* d_in, const int* in_sizes, int n_in,
                              void* d_out, int out_size, void* d_ws, size_t ws_size,
                              hipStream_t stream) {
    (void)in_sizes; (void)n_in; (void)out_size; (void)ws_size;
    const int*   tokens = (const int*)d_in[0];
    const float* emb    = (const float*)d_in[1];
    const float* W      = (const float*)d_in[2];
    const float* U      = (const float*)d_in[3];
    const float* b      = (const float*)d_in[4];
    const float* W1     = (const float*)d_in[5];
    const float* b1     = (const float*)d_in[6];
    const float* Wout   = (const float*)d_in[7];
    const float* bout   = (const float*)d_in[8];
    float* out  = (float*)d_out;
    f16*   embW = (f16*)d_ws;   // [V][384] f16 = 23 MB scratch

    hipLaunchKernelGGL(embw_kernel, dim3((V_ + K1_ROWS - 1) / K1_ROWS), dim3(384), 0, stream,
                       emb, W, b, embW);
    hipLaunchKernelGGL(gru_mfma_kernel, dim3(B_ / 32), dim3(256), 0, stream,
                       tokens, embW, U, b, W1, b1, Wout, bout, out);
}